// Round 1
// baseline (265.544 us; speedup 1.0000x reference)
//
#include <hip/hip_runtime.h>

using short8 = __attribute__((ext_vector_type(8))) short;
using f32x4  = __attribute__((ext_vector_type(4))) float;

__device__ inline unsigned short f2bf(float f) {
  unsigned u = __float_as_uint(f);
  u += 0x7fffu + ((u >> 16) & 1u);
  return (unsigned short)(u >> 16);
}
__device__ inline float bf2f(short s) {
  return __uint_as_float(((unsigned)(unsigned short)s) << 16);
}

// barrier that waits LDS only — global loads stay outstanding (pipeline!)
__device__ inline void barrier_lgkm() {
  asm volatile("s_waitcnt lgkmcnt(0)\n\ts_barrier" ::: "memory");
}

// ------- Kernel 0: ALL prep in one launch -------
// bid < 1024:             x NCHW fp32 -> xT (hi) + xTlo (residual) NHWC bf16
// 1024 <= bid < 3328:     conv weights -> wBt2[ks][o(256)][kc(32)]
// bid >= 3328:            offset weights -> wOt/wOtLo[ks][o(32, >=18 zero)][kc(32)]
__global__ __launch_bounds__(256) void prep_all(
    const float* __restrict__ x, const float* __restrict__ cw,
    const float* __restrict__ ow, unsigned short* __restrict__ xT,
    unsigned short* __restrict__ xTlo, unsigned short* __restrict__ wBt2,
    unsigned short* __restrict__ wOt, unsigned short* __restrict__ wOtLo) {
  __shared__ float tile[32 * 268];   // 34304 B (xT path only)
  int bid = blockIdx.x, tid = threadIdx.x;
  if (bid < 1024) {
    int xh = bid & 1, y = (bid >> 1) & 63, b = bid >> 7;
    int xc = tid & 31, cq = tid >> 5;
#pragma unroll 4
    for (int i = 0; i < 32; ++i) {
      int c = i * 8 + cq;
      tile[xc * 268 + c] =
          x[(((size_t)((b << 8) + c)) << 12) + (y << 6) + xh * 32 + xc];
    }
    __syncthreads();
#pragma unroll 2
    for (int i = 0; i < 8; ++i) {
      int u = i * 256 + tid;
      int site = u >> 6, c4 = u & 63;
      float4 v = *(const float4*)(tile + site * 268 + c4 * 4);
      ushort4 hi, lo;
      hi.x = f2bf(v.x); lo.x = f2bf(v.x - bf2f(hi.x));
      hi.y = f2bf(v.y); lo.y = f2bf(v.y - bf2f(hi.y));
      hi.z = f2bf(v.z); lo.z = f2bf(v.z - bf2f(hi.z));
      hi.w = f2bf(v.w); lo.w = f2bf(v.w - bf2f(hi.w));
      size_t addr = (((size_t)((b << 12) + (y << 6) + xh * 32 + site)) << 8) + c4 * 4;
      *(ushort4*)(xT + addr) = hi;
      *(ushort4*)(xTlo + addr) = lo;
    }
  } else if (bid < 3328) {
    int e = (bid - 1024) * 256 + tid;   // < 589824
    int kc = e & 31, o = (e >> 5) & 255, ks = e >> 13;
    int c = (ks & 7) * 32 + kc, kt = ks >> 3;
    wBt2[e] = f2bf(cw[(size_t)(o * 256 + c) * 9 + kt]);
  } else {
    int e = (bid - 3328) * 256 + tid;   // < 73728
    int kc = e & 31, o = (e >> 5) & 31, ks = e >> 10;
    int c = (ks & 7) * 32 + kc, kt = ks >> 3;
    float v = (o < 18) ? ow[(size_t)(o * 256 + c) * 9 + kt] : 0.f;
    unsigned short hi = f2bf(v);
    wOt[e] = hi;
    wOtLo[e] = f2bf(v - bf2f(hi));
  }
}

// ------- offset-conv helpers -------
__device__ inline void gatherOff2(const unsigned short* xT, const unsigned short* xTlo,
                                  const unsigned short* zp, int b, int h, int p16,
                                  int q, int ccg, int ky, int kx,
                                  short8* gh, short8* gl) {
  int y = h + ky - 1;
  bool yv = (unsigned)y < 64u;
  int yc = min(max(y, 0), 63);
#pragma unroll
  for (int i = 0; i < 4; ++i) {
    int px = i * 16 + p16;
    int xx = px + kx - 1;
    bool v = yv && ((unsigned)xx < 64u);
    int xc = min(max(xx, 0), 63);
    size_t base = (((size_t)((b << 12) + (yc << 6) + xc)) << 8) + ccg * 32 + q * 8;
    const unsigned short* ph = v ? (xT + base) : zp;
    const unsigned short* pl = v ? (xTlo + base) : zp;
    gh[i] = *(const short8*)ph;
    gl[i] = *(const short8*)pl;
  }
}
__device__ inline void loadBOff2(const unsigned short* wOt, const unsigned short* wOtLo,
                                 int ks, int m16, int quad, short8* bh, short8* bl) {
  const unsigned short* bp = wOt + (ks << 10) + m16 * 32 + quad * 8;
  const unsigned short* bq = wOtLo + (ks << 10) + m16 * 32 + quad * 8;
  bh[0] = *(const short8*)bp;  bh[1] = *(const short8*)(bp + 512);
  bl[0] = *(const short8*)bq;  bl[1] = *(const short8*)(bq + 512);
}

// ------- Kernel 1: offset conv via MFMA — barrier-free, 8-way K-split -------
// grid 4096 = ccq(8) x h(64) x b(8); 1 wave/block.
// SINGLE-buffered wave-local LDS (same-wave DS ops are in-order, so the
// iter-t reads always complete before iter-t+1 writes): 10.2 KB/block ->
// ~15 blocks/CU resident (was LDS-capped at 7) for 2x latency hiding.
// Wave: M=64, N=32, K=288 (fixed 32-ch chunk, taps 0..8). hi/lo numerics.
// Partial -> overlay channels 100 + ccq*18 + o of `out` (rewritten later by
// deform_main's epilogue; writer touches only row h — race-free).
__global__ __launch_bounds__(64) void offset_conv3(
    const unsigned short* __restrict__ xT, const unsigned short* __restrict__ xTlo,
    const unsigned short* __restrict__ wOt, const unsigned short* __restrict__ wOtLo,
    const unsigned short* __restrict__ zp, float* out) {
  __shared__ unsigned short Ah[2560], Al[2560];   // [64][40] each, single buf
  int lane = threadIdx.x;
  int bid = blockIdx.x;
  int b = bid & 7, h = (bid >> 3) & 63, ccq = bid >> 9;
  int m16 = lane & 15, quad = lane >> 4;
  int p16 = lane >> 2, q = lane & 3;
  f32x4 acc[4][2];
#pragma unroll
  for (int mt = 0; mt < 4; ++mt)
#pragma unroll
    for (int j = 0; j < 2; ++j) acc[mt][j] = (f32x4){0.f, 0.f, 0.f, 0.f};

  short8 gh[4], gl[4], bh[2], bl[2];
  gatherOff2(xT, xTlo, zp, b, h, p16, q, ccq, 0, 0, gh, gl);
  loadBOff2(wOt, wOtLo, ccq, m16, quad, bh, bl);

  for (int it = 0; it < 9; ++it) {
#pragma unroll
    for (int i = 0; i < 4; ++i) {
      int px = i * 16 + p16;
      *(short8*)(Ah + px * 40 + q * 8) = gh[i];
      *(short8*)(Al + px * 40 + q * 8) = gl[i];
    }
    int jn = (it < 8) ? it + 1 : 8;     // tap index (clamped; last discarded)
    int kyn = jn / 3, kxn = jn - kyn * 3;
    short8 ghn[4], gln[4], bhn[2], bln[2];
    loadBOff2(wOt, wOtLo, jn * 8 + ccq, m16, quad, bhn, bln);
    gatherOff2(xT, xTlo, zp, b, h, p16, q, ccq, kyn, kxn, ghn, gln);
    // wave-local LDS: same-wave DS ordering, no barrier needed
#pragma unroll
    for (int mt = 0; mt < 4; ++mt) {
      short8 ah = *(const short8*)(Ah + (mt * 16 + m16) * 40 + quad * 8);
      short8 al = *(const short8*)(Al + (mt * 16 + m16) * 40 + quad * 8);
#pragma unroll
      for (int j = 0; j < 2; ++j) {
        acc[mt][j] = __builtin_amdgcn_mfma_f32_16x16x32_bf16(ah, bh[j], acc[mt][j], 0, 0, 0);
        acc[mt][j] = __builtin_amdgcn_mfma_f32_16x16x32_bf16(al, bh[j], acc[mt][j], 0, 0, 0);
        acc[mt][j] = __builtin_amdgcn_mfma_f32_16x16x32_bf16(ah, bl[j], acc[mt][j], 0, 0, 0);
      }
    }
#pragma unroll
    for (int i = 0; i < 4; ++i) { gh[i] = ghn[i]; gl[i] = gln[i]; }
    bh[0] = bhn[0]; bh[1] = bhn[1]; bl[0] = bln[0]; bl[1] = bln[1];
  }
  // epilogue: D row = px (mt*16+quad*4+r), col = o (j*16+m16)
#pragma unroll
  for (int j = 0; j < 2; ++j) {
    int o = j * 16 + m16;
    if (o < 18) {
      float* po = out + (((size_t)((b << 8) + 100 + ccq * 18 + o)) << 12) + (h << 6);
#pragma unroll
      for (int mt = 0; mt < 4; ++mt)
#pragma unroll
        for (int rr = 0; rr < 4; ++rr)
          po[mt * 16 + quad * 4 + rr] = acc[mt][j][rr];
    }
  }
}

// ------- deform_main helpers (verified) -------
__device__ inline void gather4(const unsigned short* __restrict__ xT,
                               int bbase, int q, int jt,
                               const int2* cif2, const float4* cwf4,
                               int px, short8* g, float4& wq) {
  int cc = jt / 9, kt = jt - cc * 9;
  int2 si = cif2[kt * 64 + px];
  wq = cwf4[kt * 64 + px];
  const unsigned short* base = xT + (size_t)(unsigned)(bbase + cc * 32 + q * 8);
  g[0] = *(const short8*)(base + si.x);
  g[1] = *(const short8*)(base + si.x + 256);
  g[2] = *(const short8*)(base + si.y);
  g[3] = *(const short8*)(base + si.y + 256);
}
__device__ inline void loadB(const unsigned short* __restrict__ wBt2, int wv,
                             int m16, int quad, int jt, short8* bf) {
  int cc = jt / 9, kt = jt - cc * 9;
  int ks = kt * 8 + cc;
  const unsigned short* bp =
      wBt2 + ((size_t)ks << 13) + (wv << 11) + m16 * 32 + quad * 8;
#pragma unroll
  for (int j = 0; j < 4; ++j)
    bf[j] = *(const short8*)(bp + j * 512);
}

// ------- Kernel 2: fused sample + MFMA GEMM (reads offset overlay from out) -------
// 512 threads = 8 waves = 2 K-groups x 4 waves. Group kg handles cc in
// [kg*4, kg*4+4) (36 of the 72 K-iters) into its own double-buffered At
// tile; partial accumulators are summed through LDS at the end. Same grid
// (512 = b x h) but 16 waves/CU instead of 8 -> 4 waves/SIMD latency hiding.
__global__ __launch_bounds__(512, 4) void deform_main(
    const unsigned short* __restrict__ xT, const float* __restrict__ offb,
    const unsigned short* __restrict__ wBt2, float* out) {
  __shared__ float4 smem4[2144];               // 34304 B
  char* smem = (char*)smem4;
  float4* cwf4 = (float4*)smem;                          // 9216 B
  int2*   cif2 = (int2*)(smem + 9216);                   // 4608 B
  unsigned short* At = (unsigned short*)(smem + 13824);  // 2 grp x 2 buf x [64][40]

  int tid = threadIdx.x, lane = tid & 63, wave = tid >> 6;
  int kg = wave >> 2, wv = wave & 3;
  int b = blockIdx.x & 7, h = blockIdx.x >> 3;

  // --- coord precompute; offsets = sum of 8 K-split partials + bias ---
  size_t bb = ((size_t)(b << 8)) << 12;
  for (int it = tid; it < 576; it += 512) {
    int k = it >> 6, px = it & 63;
    int ky = k / 3, kx = k - ky * 3;
    int idx = (h << 6) + px;
    float dy = offb[2 * k], dx = offb[2 * k + 1];
#pragma unroll
    for (int qq = 0; qq < 8; ++qq) {
      dy += out[bb + (((size_t)(100 + qq * 18 + 2 * k)) << 12) + idx];
      dx += out[bb + (((size_t)(101 + qq * 18 + 2 * k)) << 12) + idx];
    }
    float py = (float)(h - 1 + ky) + dy;
    float pxx = (float)(px - 1 + kx) + dx;
    float y0f = floorf(py), x0f = floorf(pxx);
    int y0 = (int)y0f, x0 = (int)x0f;
    float wy1 = py - y0f, wx1 = pxx - x0f;
    int xb; float wxl, wxr;
    if (x0 >= 0 && x0 <= 62)      { xb = x0; wxl = 1.f - wx1; wxr = wx1; }
    else if (x0 == -1)            { xb = 0;  wxl = wx1;       wxr = 0.f; }
    else if (x0 == 63)            { xb = 62; wxl = 0.f;       wxr = 1.f - wx1; }
    else                          { xb = 0;  wxl = 0.f;       wxr = 0.f; }
    float wy0v = ((unsigned)y0 < 64u) ? (1.f - wy1) : 0.f;
    float wy1v = ((unsigned)(y0 + 1) < 64u) ? wy1 : 0.f;
    int yc0 = min(max(y0, 0), 63), yc1 = min(max(y0 + 1, 0), 63);
    cwf4[it] = make_float4(wy0v * wxl, wy0v * wxr, wy1v * wxl, wy1v * wxr);
    cif2[it] = make_int2(((yc0 << 6) + xb) << 8, ((yc1 << 6) + xb) << 8);
  }
  __syncthreads();

  int m16 = lane & 15, quad = lane >> 4;
  int px = wv * 16 + (lane >> 2);
  int q  = lane & 3;
  int bbase = b << 20;
  f32x4 acc[4][4];
#pragma unroll
  for (int i = 0; i < 4; ++i)
#pragma unroll
    for (int j = 0; j < 4; ++j) acc[i][j] = (f32x4){0.f, 0.f, 0.f, 0.f};

  unsigned short* Abase = At + kg * 5120;
  const int jt0 = kg * 36;

  short8 g[4]; float4 wq; short8 bcur[4];
  gather4(xT, bbase, q, jt0, cif2, cwf4, px, g, wq);
  loadB(wBt2, wv, m16, quad, jt0, bcur);

  for (int it = 0; it < 36; ++it) {
    int buf = it & 1;
    short8 av;
#pragma unroll
    for (int i = 0; i < 8; ++i) {
      float v = wq.x * bf2f(g[0][i]) + wq.y * bf2f(g[1][i]) +
                wq.z * bf2f(g[2][i]) + wq.w * bf2f(g[3][i]);
      av[i] = (short)f2bf(v);
    }
    *(short8*)(Abase + buf * 2560 + px * 40 + q * 8) = av;
    int jn = jt0 + ((it < 35) ? it + 1 : 35);
    short8 bnext[4], gn[4]; float4 wqn;
    loadB(wBt2, wv, m16, quad, jn, bnext);
    gather4(xT, bbase, q, jn, cif2, cwf4, px, gn, wqn);
    barrier_lgkm();
    short8 af[4];
#pragma unroll
    for (int mt = 0; mt < 4; ++mt)
      af[mt] = *(const short8*)(Abase + buf * 2560 + (mt * 16 + m16) * 40 + quad * 8);
#pragma unroll
    for (int mt = 0; mt < 4; ++mt)
#pragma unroll
      for (int j = 0; j < 4; ++j)
        acc[mt][j] = __builtin_amdgcn_mfma_f32_16x16x32_bf16(af[mt], bcur[j],
                                                             acc[mt][j], 0, 0, 0);
#pragma unroll
    for (int i = 0; i < 4; ++i) g[i] = gn[i];
    wq = wqn;
#pragma unroll
    for (int j = 0; j < 4; ++j) bcur[j] = bnext[j];
  }

  // ---- cross-group reduction: kg=1 partials -> kg=0 accumulators ----
  __syncthreads();                    // all At/coord reads done; reuse smem
  f32x4* red = (f32x4*)smem;          // 16 KB, [mt][wv][lane] (conflict-free)
#pragma unroll
  for (int j = 0; j < 4; ++j) {
    if (kg == 1) {
#pragma unroll
      for (int mt = 0; mt < 4; ++mt)
        red[(mt * 4 + wv) * 64 + lane] = acc[mt][j];
    }
    __syncthreads();
    if (kg == 0) {
#pragma unroll
      for (int mt = 0; mt < 4; ++mt) {
        f32x4 v = red[(mt * 4 + wv) * 64 + lane];
        acc[mt][j][0] += v[0]; acc[mt][j][1] += v[1];
        acc[mt][j][2] += v[2]; acc[mt][j][3] += v[3];
      }
    }
    __syncthreads();
  }

  // ---- epilogue (kg=0 waves): direct float4 stores from D-fragments ----
  // o = wv*64 + j*16 + m16 ; px = mt*16 + quad*4 + r (r contiguous)
  if (kg == 0) {
#pragma unroll
    for (int j = 0; j < 4; ++j) {
      int o = wv * 64 + j * 16 + m16;
      float* po = out + (((size_t)((b << 8) + o)) << 12) + (h << 6) + quad * 4;
#pragma unroll
      for (int mt = 0; mt < 4; ++mt) {
        float4 v = make_float4(acc[mt][j][0], acc[mt][j][1], acc[mt][j][2],
                               acc[mt][j][3]);
        *(float4*)(po + mt * 16) = v;
      }
    }
  }
}

extern "C" void kernel_launch(void* const* d_in, const int* in_sizes, int n_in,
                              void* d_out, int out_size, void* d_ws, size_t ws_size,
                              hipStream_t stream) {
  const float* x     = (const float*)d_in[0];
  const float* offw  = (const float*)d_in[1];
  const float* offb  = (const float*)d_in[2];
  const float* convw = (const float*)d_in[3];
  float* out = (float*)d_out;

  char* ws = (char*)d_ws;
  unsigned short* wOt   = (unsigned short*)ws;                // 147,456 B
  unsigned short* wOtLo = (unsigned short*)(ws + 147456);     // 147,456 B
  unsigned short* wBt2  = (unsigned short*)(ws + 294912);     // 1,179,648 B
  unsigned short* xT    = (unsigned short*)(ws + 1474560);    // 16,777,216 B
  unsigned short* xTlo  = (unsigned short*)(ws + 18251776);   // 16,777,216 B (end 35,028,992)
  const unsigned short* zp = wOt + 768;   // ks=0, o=24 row: guaranteed zeros

  prep_all<<<3616, 256, 0, stream>>>(x, convw, offw, xT, xTlo, wBt2, wOt, wOtLo);
  offset_conv3<<<4096, 64, 0, stream>>>(xT, xTlo, wOt, wOtLo, zp, out);
  deform_main<<<512, 512, 0, stream>>>(xT, offb, wBt2, out);
}

// Round 2
// 251.161 us; speedup vs baseline: 1.0573x; 1.0573x over previous
//
#include <hip/hip_runtime.h>
#include <hip/hip_fp16.h>

using short8 = __attribute__((ext_vector_type(8))) short;
using f32x4  = __attribute__((ext_vector_type(4))) float;

__device__ inline unsigned short f2bf(float f) {
  unsigned u = __float_as_uint(f);
  u += 0x7fffu + ((u >> 16) & 1u);
  return (unsigned short)(u >> 16);
}
__device__ inline float bf2f(short s) {
  return __uint_as_float(((unsigned)(unsigned short)s) << 16);
}

// barrier that waits LDS only — global loads stay outstanding (pipeline!)
__device__ inline void barrier_lgkm() {
  asm volatile("s_waitcnt lgkmcnt(0)\n\ts_barrier" ::: "memory");
}

// ------- Kernel 0: ALL prep in one launch -------
// bid < 1024:             x NCHW fp32 -> xT (hi) + xTlo (residual) NHWC bf16
// 1024 <= bid < 3328:     conv weights -> wBt2[ks][o(256)][kc(32)]
// bid >= 3328:            offset weights -> wOt/wOtLo[ks][o(32, >=18 zero)][kc(32)]
// NOTE: the o>=18 zero rows of wOt double as the (b,h) pair-flags for
// deform_main's kg-split sync — re-zeroed here every launch.
__global__ __launch_bounds__(256) void prep_all(
    const float* __restrict__ x, const float* __restrict__ cw,
    const float* __restrict__ ow, unsigned short* __restrict__ xT,
    unsigned short* __restrict__ xTlo, unsigned short* __restrict__ wBt2,
    unsigned short* __restrict__ wOt, unsigned short* __restrict__ wOtLo) {
  __shared__ float tile[32 * 268];   // 34304 B (xT path only)
  int bid = blockIdx.x, tid = threadIdx.x;
  if (bid < 1024) {
    int xh = bid & 1, y = (bid >> 1) & 63, b = bid >> 7;
    int xc = tid & 31, cq = tid >> 5;
#pragma unroll 4
    for (int i = 0; i < 32; ++i) {
      int c = i * 8 + cq;
      tile[xc * 268 + c] =
          x[(((size_t)((b << 8) + c)) << 12) + (y << 6) + xh * 32 + xc];
    }
    __syncthreads();
#pragma unroll 2
    for (int i = 0; i < 8; ++i) {
      int u = i * 256 + tid;
      int site = u >> 6, c4 = u & 63;
      float4 v = *(const float4*)(tile + site * 268 + c4 * 4);
      ushort4 hi, lo;
      hi.x = f2bf(v.x); lo.x = f2bf(v.x - bf2f(hi.x));
      hi.y = f2bf(v.y); lo.y = f2bf(v.y - bf2f(hi.y));
      hi.z = f2bf(v.z); lo.z = f2bf(v.z - bf2f(hi.z));
      hi.w = f2bf(v.w); lo.w = f2bf(v.w - bf2f(hi.w));
      size_t addr = (((size_t)((b << 12) + (y << 6) + xh * 32 + site)) << 8) + c4 * 4;
      *(ushort4*)(xT + addr) = hi;
      *(ushort4*)(xTlo + addr) = lo;
    }
  } else if (bid < 3328) {
    int e = (bid - 1024) * 256 + tid;   // < 589824
    int kc = e & 31, o = (e >> 5) & 255, ks = e >> 13;
    int c = (ks & 7) * 32 + kc, kt = ks >> 3;
    wBt2[e] = f2bf(cw[(size_t)(o * 256 + c) * 9 + kt]);
  } else {
    int e = (bid - 3328) * 256 + tid;   // < 73728
    int kc = e & 31, o = (e >> 5) & 31, ks = e >> 10;
    int c = (ks & 7) * 32 + kc, kt = ks >> 3;
    float v = (o < 18) ? ow[(size_t)(o * 256 + c) * 9 + kt] : 0.f;
    unsigned short hi = f2bf(v);
    wOt[e] = hi;
    wOtLo[e] = f2bf(v - bf2f(hi));
  }
}

// ------- offset-conv helpers -------
__device__ inline void gatherOff2(const unsigned short* xT, const unsigned short* xTlo,
                                  const unsigned short* zp, int b, int h, int p16,
                                  int q, int ccg, int ky, int kx,
                                  short8* gh, short8* gl) {
  int y = h + ky - 1;
  bool yv = (unsigned)y < 64u;
  int yc = min(max(y, 0), 63);
#pragma unroll
  for (int i = 0; i < 4; ++i) {
    int px = i * 16 + p16;
    int xx = px + kx - 1;
    bool v = yv && ((unsigned)xx < 64u);
    int xc = min(max(xx, 0), 63);
    size_t base = (((size_t)((b << 12) + (yc << 6) + xc)) << 8) + ccg * 32 + q * 8;
    const unsigned short* ph = v ? (xT + base) : zp;
    const unsigned short* pl = v ? (xTlo + base) : zp;
    gh[i] = *(const short8*)ph;
    gl[i] = *(const short8*)pl;
  }
}
__device__ inline void loadBOff2(const unsigned short* wOt, const unsigned short* wOtLo,
                                 int ks, int m16, int quad, short8* bh, short8* bl) {
  const unsigned short* bp = wOt + (ks << 10) + m16 * 32 + quad * 8;
  const unsigned short* bq = wOtLo + (ks << 10) + m16 * 32 + quad * 8;
  bh[0] = *(const short8*)bp;  bh[1] = *(const short8*)(bp + 512);
  bl[0] = *(const short8*)bq;  bl[1] = *(const short8*)(bq + 512);
}

// ------- Kernel 1: offset conv via MFMA — barrier-free, 8-way K-split -------
// grid 4096 = ccq(8) x h(64) x b(8); 1 wave/block.
// SINGLE-buffered wave-local LDS (same-wave DS ops are in-order): 10.2 KB
// -> ~15 blocks/CU resident for latency hiding.
__global__ __launch_bounds__(64) void offset_conv3(
    const unsigned short* __restrict__ xT, const unsigned short* __restrict__ xTlo,
    const unsigned short* __restrict__ wOt, const unsigned short* __restrict__ wOtLo,
    const unsigned short* __restrict__ zp, float* out) {
  __shared__ unsigned short Ah[2560], Al[2560];   // [64][40] each, single buf
  int lane = threadIdx.x;
  int bid = blockIdx.x;
  int b = bid & 7, h = (bid >> 3) & 63, ccq = bid >> 9;
  int m16 = lane & 15, quad = lane >> 4;
  int p16 = lane >> 2, q = lane & 3;
  f32x4 acc[4][2];
#pragma unroll
  for (int mt = 0; mt < 4; ++mt)
#pragma unroll
    for (int j = 0; j < 2; ++j) acc[mt][j] = (f32x4){0.f, 0.f, 0.f, 0.f};

  short8 gh[4], gl[4], bh[2], bl[2];
  gatherOff2(xT, xTlo, zp, b, h, p16, q, ccq, 0, 0, gh, gl);
  loadBOff2(wOt, wOtLo, ccq, m16, quad, bh, bl);

  for (int it = 0; it < 9; ++it) {
#pragma unroll
    for (int i = 0; i < 4; ++i) {
      int px = i * 16 + p16;
      *(short8*)(Ah + px * 40 + q * 8) = gh[i];
      *(short8*)(Al + px * 40 + q * 8) = gl[i];
    }
    int jn = (it < 8) ? it + 1 : 8;     // tap index (clamped; last discarded)
    int kyn = jn / 3, kxn = jn - kyn * 3;
    short8 ghn[4], gln[4], bhn[2], bln[2];
    loadBOff2(wOt, wOtLo, jn * 8 + ccq, m16, quad, bhn, bln);
    gatherOff2(xT, xTlo, zp, b, h, p16, q, ccq, kyn, kxn, ghn, gln);
    // wave-local LDS: same-wave DS ordering, no barrier needed
#pragma unroll
    for (int mt = 0; mt < 4; ++mt) {
      short8 ah = *(const short8*)(Ah + (mt * 16 + m16) * 40 + quad * 8);
      short8 al = *(const short8*)(Al + (mt * 16 + m16) * 40 + quad * 8);
#pragma unroll
      for (int j = 0; j < 2; ++j) {
        acc[mt][j] = __builtin_amdgcn_mfma_f32_16x16x32_bf16(ah, bh[j], acc[mt][j], 0, 0, 0);
        acc[mt][j] = __builtin_amdgcn_mfma_f32_16x16x32_bf16(al, bh[j], acc[mt][j], 0, 0, 0);
        acc[mt][j] = __builtin_amdgcn_mfma_f32_16x16x32_bf16(ah, bl[j], acc[mt][j], 0, 0, 0);
      }
    }
#pragma unroll
    for (int i = 0; i < 4; ++i) { gh[i] = ghn[i]; gl[i] = gln[i]; }
    bh[0] = bhn[0]; bh[1] = bhn[1]; bl[0] = bln[0]; bl[1] = bln[1];
  }
  // epilogue: D row = px (mt*16+quad*4+r), col = o (j*16+m16)
#pragma unroll
  for (int j = 0; j < 2; ++j) {
    int o = j * 16 + m16;
    if (o < 18) {
      float* po = out + (((size_t)((b << 8) + 100 + ccq * 18 + o)) << 12) + (h << 6);
#pragma unroll
      for (int mt = 0; mt < 4; ++mt)
#pragma unroll
        for (int rr = 0; rr < 4; ++rr)
          po[mt * 16 + quad * 4 + rr] = acc[mt][j][rr];
    }
  }
}

// ------- deform_main helpers (verified) -------
__device__ inline void gather4(const unsigned short* __restrict__ xT,
                               int bbase, int q, int jt,
                               const int2* cif2, const float4* cwf4,
                               int px, short8* g, float4& wq) {
  int cc = jt / 9, kt = jt - cc * 9;
  int2 si = cif2[kt * 64 + px];
  wq = cwf4[kt * 64 + px];
  const unsigned short* base = xT + (size_t)(unsigned)(bbase + cc * 32 + q * 8);
  g[0] = *(const short8*)(base + si.x);
  g[1] = *(const short8*)(base + si.x + 256);
  g[2] = *(const short8*)(base + si.y);
  g[3] = *(const short8*)(base + si.y + 256);
}
__device__ inline void loadB(const unsigned short* __restrict__ wBt2, int wave,
                             int m16, int quad, int jt, short8* bf) {
  int cc = jt / 9, kt = jt - cc * 9;
  int ks = kt * 8 + cc;
  const unsigned short* bp =
      wBt2 + ((size_t)ks << 13) + (wave << 11) + m16 * 32 + quad * 8;
#pragma unroll
  for (int j = 0; j < 4; ++j)
    bf[j] = *(const short8*)(bp + j * 512);
}

// ------- Kernel 2: fused sample + MFMA GEMM, K-split across block PAIRS -------
// grid 1024 = kg(1b) x b(3b) x h(6b), kg interleaved in bid.
// Each block runs the proven 72-VGPR round-0 wave body over 36 of 72 K-iters
// (kg0: cc 0..3, kg1: cc 4..7). kg1 stores its partial as f16 into the dead
// xTlo region and raises a device-scope flag (wOt zero rows); kg0 spins on
// the flag, adds the partner partial in f32, writes out. launch_bounds(256,4)
// + 24KB LDS guarantees all 1024 blocks co-resident -> spin is deadlock-free
// under any dispatch order.
__global__ __launch_bounds__(256, 4) void deform_main(
    const unsigned short* __restrict__ xT, const float* __restrict__ offb,
    const unsigned short* __restrict__ wBt2, float* out,
    unsigned short* __restrict__ part, char* __restrict__ flagB) {
  __shared__ float4 smem4[1504];               // 24064 B
  char* smem = (char*)smem4;
  float4* cwf4 = (float4*)smem;                          // 9216 B
  int2*   cif2 = (int2*)(smem + 9216);                   // 4608 B
  unsigned short* At = (unsigned short*)(smem + 13824);  // 2 x [64][40] bf16

  int tid = threadIdx.x, lane = tid & 63, wave = tid >> 6;
  int bid = blockIdx.x;
  int kg = bid & 1, b = (bid >> 1) & 7, h = bid >> 4;

  // --- coord precompute; offsets = sum of 8 K-split partials + bias ---
  size_t bb = ((size_t)(b << 8)) << 12;
  for (int it = tid; it < 576; it += 256) {
    int k = it >> 6, px = it & 63;
    int ky = k / 3, kx = k - ky * 3;
    int idx = (h << 6) + px;
    float dy = offb[2 * k], dx = offb[2 * k + 1];
#pragma unroll
    for (int qq = 0; qq < 8; ++qq) {
      dy += out[bb + (((size_t)(100 + qq * 18 + 2 * k)) << 12) + idx];
      dx += out[bb + (((size_t)(101 + qq * 18 + 2 * k)) << 12) + idx];
    }
    float py = (float)(h - 1 + ky) + dy;
    float pxx = (float)(px - 1 + kx) + dx;
    float y0f = floorf(py), x0f = floorf(pxx);
    int y0 = (int)y0f, x0 = (int)x0f;
    float wy1 = py - y0f, wx1 = pxx - x0f;
    int xb; float wxl, wxr;
    if (x0 >= 0 && x0 <= 62)      { xb = x0; wxl = 1.f - wx1; wxr = wx1; }
    else if (x0 == -1)            { xb = 0;  wxl = wx1;       wxr = 0.f; }
    else if (x0 == 63)            { xb = 62; wxl = 0.f;       wxr = 1.f - wx1; }
    else                          { xb = 0;  wxl = 0.f;       wxr = 0.f; }
    float wy0v = ((unsigned)y0 < 64u) ? (1.f - wy1) : 0.f;
    float wy1v = ((unsigned)(y0 + 1) < 64u) ? wy1 : 0.f;
    int yc0 = min(max(y0, 0), 63), yc1 = min(max(y0 + 1, 0), 63);
    cwf4[it] = make_float4(wy0v * wxl, wy0v * wxr, wy1v * wxl, wy1v * wxr);
    cif2[it] = make_int2(((yc0 << 6) + xb) << 8, ((yc1 << 6) + xb) << 8);
  }
  __syncthreads();

  int m16 = lane & 15, quad = lane >> 4;
  int px = wave * 16 + (lane >> 2);
  int q  = lane & 3;
  int bbase = b << 20;
  f32x4 acc[4][4];
#pragma unroll
  for (int i = 0; i < 4; ++i)
#pragma unroll
    for (int j = 0; j < 4; ++j) acc[i][j] = (f32x4){0.f, 0.f, 0.f, 0.f};

  const int jt0 = kg * 36;
  short8 g[4]; float4 wq; short8 bcur[4];
  gather4(xT, bbase, q, jt0, cif2, cwf4, px, g, wq);
  loadB(wBt2, wave, m16, quad, jt0, bcur);

  for (int it = 0; it < 36; ++it) {
    int buf = it & 1;
    short8 av;
#pragma unroll
    for (int i = 0; i < 8; ++i) {
      float v = wq.x * bf2f(g[0][i]) + wq.y * bf2f(g[1][i]) +
                wq.z * bf2f(g[2][i]) + wq.w * bf2f(g[3][i]);
      av[i] = (short)f2bf(v);
    }
    *(short8*)(At + buf * 2560 + px * 40 + q * 8) = av;
    int jn = jt0 + ((it < 35) ? it + 1 : 35);
    short8 bnext[4], gn[4]; float4 wqn;
    loadB(wBt2, wave, m16, quad, jn, bnext);
    gather4(xT, bbase, q, jn, cif2, cwf4, px, gn, wqn);
    barrier_lgkm();
    short8 af[4];
#pragma unroll
    for (int mt = 0; mt < 4; ++mt)
      af[mt] = *(const short8*)(At + buf * 2560 + (mt * 16 + m16) * 40 + quad * 8);
#pragma unroll
    for (int mt = 0; mt < 4; ++mt)
#pragma unroll
      for (int j = 0; j < 4; ++j)
        acc[mt][j] = __builtin_amdgcn_mfma_f32_16x16x32_bf16(af[mt], bcur[j],
                                                             acc[mt][j], 0, 0, 0);
#pragma unroll
    for (int i = 0; i < 4; ++i) g[i] = gn[i];
    wq = wqn;
#pragma unroll
    for (int j = 0; j < 4; ++j) bcur[j] = bnext[j];
  }

  // ---- pair sync + epilogue ----
  // flag(b,h) lives in wOt's guaranteed-zero rows: byte b*2048 + 1600 + h*4
  int* fl = (int*)(flagB + b * 2048 + 1600 + (h << 2));
  if (kg == 1) {
    // store f16 partial (same (o,px) layout as out, but 2B elems)
#pragma unroll
    for (int j = 0; j < 4; ++j) {
      int o = wave * 64 + j * 16 + m16;
      size_t rowoff = (((size_t)((b << 8) + o)) << 12) + (h << 6) + quad * 4;
      __half* pp = (__half*)part + rowoff;
#pragma unroll
      for (int mt = 0; mt < 4; ++mt) {
        __half2 h0 = __floats2half2_rn(acc[mt][j][0], acc[mt][j][1]);
        __half2 h1 = __floats2half2_rn(acc[mt][j][2], acc[mt][j][3]);
        uint2 u2; u2.x = *(unsigned*)&h0; u2.y = *(unsigned*)&h1;
        *(uint2*)(pp + mt * 16) = u2;
      }
    }
    asm volatile("s_waitcnt vmcnt(0)" ::: "memory");
    __syncthreads();                      // all threads' stores drained
    if (tid == 0) {
      __threadfence();                    // device-scope release
      atomicAdd(fl, 1);                   // device-scope by default (m20)
    }
  } else {
    if (tid == 0) {
      while (atomicAdd(fl, 0) == 0) __builtin_amdgcn_s_sleep(2);
      __threadfence();                    // device-scope acquire
    }
    __syncthreads();
#pragma unroll
    for (int j = 0; j < 4; ++j) {
      int o = wave * 64 + j * 16 + m16;
      size_t rowoff = (((size_t)((b << 8) + o)) << 12) + (h << 6) + quad * 4;
      const __half* pp = (const __half*)part + rowoff;
      float* po = out + rowoff;
#pragma unroll
      for (int mt = 0; mt < 4; ++mt) {
        uint2 u2 = *(const uint2*)(pp + mt * 16);
        __half2 h0 = *(__half2*)&u2.x, h1 = *(__half2*)&u2.y;
        float2 f0 = __half22float2(h0), f1 = __half22float2(h1);
        float4 v = make_float4(acc[mt][j][0] + f0.x, acc[mt][j][1] + f0.y,
                               acc[mt][j][2] + f1.x, acc[mt][j][3] + f1.y);
        *(float4*)(po + mt * 16) = v;
      }
    }
  }
}

extern "C" void kernel_launch(void* const* d_in, const int* in_sizes, int n_in,
                              void* d_out, int out_size, void* d_ws, size_t ws_size,
                              hipStream_t stream) {
  const float* x     = (const float*)d_in[0];
  const float* offw  = (const float*)d_in[1];
  const float* offb  = (const float*)d_in[2];
  const float* convw = (const float*)d_in[3];
  float* out = (float*)d_out;

  char* ws = (char*)d_ws;
  unsigned short* wOt   = (unsigned short*)ws;                // 147,456 B
  unsigned short* wOtLo = (unsigned short*)(ws + 147456);     // 147,456 B
  unsigned short* wBt2  = (unsigned short*)(ws + 294912);     // 1,179,648 B
  unsigned short* xT    = (unsigned short*)(ws + 1474560);    // 16,777,216 B
  unsigned short* xTlo  = (unsigned short*)(ws + 18251776);   // 16,777,216 B (end 35,028,992)
  const unsigned short* zp = wOt + 768;   // ks=0, o=24 row: guaranteed zeros

  prep_all<<<3616, 256, 0, stream>>>(x, convw, offw, xT, xTlo, wBt2, wOt, wOtLo);
  offset_conv3<<<4096, 64, 0, stream>>>(xT, xTlo, wOt, wOtLo, zp, out);
  // xTlo doubles as the kg1 f16 partial buffer (dead after offset_conv3);
  // wOt zero rows double as the pair flags (re-zeroed by prep_all).
  deform_main<<<1024, 256, 0, stream>>>(xT, offb, wBt2, out, xTlo, (char*)wOt);
}

// Round 5
// 212.100 us; speedup vs baseline: 1.2520x; 1.1842x over previous
//
#include <hip/hip_runtime.h>

using short8 = __attribute__((ext_vector_type(8))) short;
using f32x4  = __attribute__((ext_vector_type(4))) float;

__device__ inline unsigned short f2bf(float f) {
  unsigned u = __float_as_uint(f);
  u += 0x7fffu + ((u >> 16) & 1u);
  return (unsigned short)(u >> 16);
}
__device__ inline float bf2f(short s) {
  return __uint_as_float(((unsigned)(unsigned short)s) << 16);
}

// barrier that waits LDS only — global loads stay outstanding (pipeline!)
__device__ inline void barrier_lgkm() {
  asm volatile("s_waitcnt lgkmcnt(0)\n\ts_barrier" ::: "memory");
}

// ------- Kernel 0: ALL prep in one launch -------
// bid < 1024:             x NCHW fp32 -> xT (hi) + xTlo (residual) NHWC bf16
// 1024 <= bid < 3328:     conv weights -> wBt2[ks][o(256)][kc(32)]
// bid >= 3328:            offset weights -> wOt/wOtLo[ks][o(32, >=18 zero)][kc(32)]
__global__ __launch_bounds__(256) void prep_all(
    const float* __restrict__ x, const float* __restrict__ cw,
    const float* __restrict__ ow, unsigned short* __restrict__ xT,
    unsigned short* __restrict__ xTlo, unsigned short* __restrict__ wBt2,
    unsigned short* __restrict__ wOt, unsigned short* __restrict__ wOtLo) {
  __shared__ float tile[32 * 268];   // 34304 B (xT path only)
  int bid = blockIdx.x, tid = threadIdx.x;
  if (bid < 1024) {
    int xh = bid & 1, y = (bid >> 1) & 63, b = bid >> 7;
    int xc = tid & 31, cq = tid >> 5;
#pragma unroll 4
    for (int i = 0; i < 32; ++i) {
      int c = i * 8 + cq;
      tile[xc * 268 + c] =
          x[(((size_t)((b << 8) + c)) << 12) + (y << 6) + xh * 32 + xc];
    }
    __syncthreads();
#pragma unroll 2
    for (int i = 0; i < 8; ++i) {
      int u = i * 256 + tid;
      int site = u >> 6, c4 = u & 63;
      float4 v = *(const float4*)(tile + site * 268 + c4 * 4);
      ushort4 hi, lo;
      hi.x = f2bf(v.x); lo.x = f2bf(v.x - bf2f(hi.x));
      hi.y = f2bf(v.y); lo.y = f2bf(v.y - bf2f(hi.y));
      hi.z = f2bf(v.z); lo.z = f2bf(v.z - bf2f(hi.z));
      hi.w = f2bf(v.w); lo.w = f2bf(v.w - bf2f(hi.w));
      size_t addr = (((size_t)((b << 12) + (y << 6) + xh * 32 + site)) << 8) + c4 * 4;
      *(ushort4*)(xT + addr) = hi;
      *(ushort4*)(xTlo + addr) = lo;
    }
  } else if (bid < 3328) {
    int e = (bid - 1024) * 256 + tid;   // < 589824
    int kc = e & 31, o = (e >> 5) & 255, ks = e >> 13;
    int c = (ks & 7) * 32 + kc, kt = ks >> 3;
    wBt2[e] = f2bf(cw[(size_t)(o * 256 + c) * 9 + kt]);
  } else {
    int e = (bid - 3328) * 256 + tid;   // < 73728
    int kc = e & 31, o = (e >> 5) & 31, ks = e >> 10;
    int c = (ks & 7) * 32 + kc, kt = ks >> 3;
    float v = (o < 18) ? ow[(size_t)(o * 256 + c) * 9 + kt] : 0.f;
    unsigned short hi = f2bf(v);
    wOt[e] = hi;
    wOtLo[e] = f2bf(v - bf2f(hi));
  }
}

// ------- offset-conv helpers -------
__device__ inline void gatherOff2(const unsigned short* xT, const unsigned short* xTlo,
                                  const unsigned short* zp, int b, int h, int p16,
                                  int q, int ccg, int ky, int kx,
                                  short8* gh, short8* gl) {
  int y = h + ky - 1;
  bool yv = (unsigned)y < 64u;
  int yc = min(max(y, 0), 63);
#pragma unroll
  for (int i = 0; i < 4; ++i) {
    int px = i * 16 + p16;
    int xx = px + kx - 1;
    bool v = yv && ((unsigned)xx < 64u);
    int xc = min(max(xx, 0), 63);
    size_t base = (((size_t)((b << 12) + (yc << 6) + xc)) << 8) + ccg * 32 + q * 8;
    const unsigned short* ph = v ? (xT + base) : zp;
    const unsigned short* pl = v ? (xTlo + base) : zp;
    gh[i] = *(const short8*)ph;
    gl[i] = *(const short8*)pl;
  }
}
__device__ inline void loadBOff2(const unsigned short* wOt, const unsigned short* wOtLo,
                                 int ks, int m16, int quad, short8* bh, short8* bl) {
  const unsigned short* bp = wOt + (ks << 10) + m16 * 32 + quad * 8;
  const unsigned short* bq = wOtLo + (ks << 10) + m16 * 32 + quad * 8;
  bh[0] = *(const short8*)bp;  bh[1] = *(const short8*)(bp + 512);
  bl[0] = *(const short8*)bq;  bl[1] = *(const short8*)(bq + 512);
}

// ------- Kernel 1: offset conv via MFMA — barrier-free, 8-way K-split -------
// grid 4096 = ccq(8) x h(64) x b(8); 1 wave/block.
// SINGLE-buffered wave-local LDS (same-wave DS ops are in-order): 10.2 KB
// -> ~15 blocks/CU resident for latency hiding. (Passed in round 2.)
__global__ __launch_bounds__(64) void offset_conv3(
    const unsigned short* __restrict__ xT, const unsigned short* __restrict__ xTlo,
    const unsigned short* __restrict__ wOt, const unsigned short* __restrict__ wOtLo,
    const unsigned short* __restrict__ zp, float* out) {
  __shared__ unsigned short Ah[2560], Al[2560];   // [64][40] each, single buf
  int lane = threadIdx.x;
  int bid = blockIdx.x;
  int b = bid & 7, h = (bid >> 3) & 63, ccq = bid >> 9;
  int m16 = lane & 15, quad = lane >> 4;
  int p16 = lane >> 2, q = lane & 3;
  f32x4 acc[4][2];
#pragma unroll
  for (int mt = 0; mt < 4; ++mt)
#pragma unroll
    for (int j = 0; j < 2; ++j) acc[mt][j] = (f32x4){0.f, 0.f, 0.f, 0.f};

  short8 gh[4], gl[4], bh[2], bl[2];
  gatherOff2(xT, xTlo, zp, b, h, p16, q, ccq, 0, 0, gh, gl);
  loadBOff2(wOt, wOtLo, ccq, m16, quad, bh, bl);

  for (int it = 0; it < 9; ++it) {
#pragma unroll
    for (int i = 0; i < 4; ++i) {
      int px = i * 16 + p16;
      *(short8*)(Ah + px * 40 + q * 8) = gh[i];
      *(short8*)(Al + px * 40 + q * 8) = gl[i];
    }
    int jn = (it < 8) ? it + 1 : 8;     // tap index (clamped; last discarded)
    int kyn = jn / 3, kxn = jn - kyn * 3;
    short8 ghn[4], gln[4], bhn[2], bln[2];
    loadBOff2(wOt, wOtLo, jn * 8 + ccq, m16, quad, bhn, bln);
    gatherOff2(xT, xTlo, zp, b, h, p16, q, ccq, kyn, kxn, ghn, gln);
    // wave-local LDS: same-wave DS ordering, no barrier needed
#pragma unroll
    for (int mt = 0; mt < 4; ++mt) {
      short8 ah = *(const short8*)(Ah + (mt * 16 + m16) * 40 + quad * 8);
      short8 al = *(const short8*)(Al + (mt * 16 + m16) * 40 + quad * 8);
#pragma unroll
      for (int j = 0; j < 2; ++j) {
        acc[mt][j] = __builtin_amdgcn_mfma_f32_16x16x32_bf16(ah, bh[j], acc[mt][j], 0, 0, 0);
        acc[mt][j] = __builtin_amdgcn_mfma_f32_16x16x32_bf16(al, bh[j], acc[mt][j], 0, 0, 0);
        acc[mt][j] = __builtin_amdgcn_mfma_f32_16x16x32_bf16(ah, bl[j], acc[mt][j], 0, 0, 0);
      }
    }
#pragma unroll
    for (int i = 0; i < 4; ++i) { gh[i] = ghn[i]; gl[i] = gln[i]; }
    bh[0] = bhn[0]; bh[1] = bhn[1]; bl[0] = bln[0]; bl[1] = bln[1];
  }
  // epilogue: D row = px (mt*16+quad*4+r), col = o (j*16+m16)
#pragma unroll
  for (int j = 0; j < 2; ++j) {
    int o = j * 16 + m16;
    if (o < 18) {
      float* po = out + (((size_t)((b << 8) + 100 + ccq * 18 + o)) << 12) + (h << 6);
#pragma unroll
      for (int mt = 0; mt < 4; ++mt)
#pragma unroll
        for (int rr = 0; rr < 4; ++rr)
          po[mt * 16 + quad * 4 + rr] = acc[mt][j][rr];
    }
  }
}

// ------- deform_main helpers -------
__device__ inline void gather4(const unsigned short* __restrict__ xT,
                               int bbase, int q, int jt,
                               const int2* cif2, const float4* cwf4,
                               int lpx, short8* g, float4& wq) {
  int cc = jt / 9, kt = jt - cc * 9;
  int2 si = cif2[kt * 32 + lpx];
  wq = cwf4[kt * 32 + lpx];
  const unsigned short* base = xT + (size_t)(unsigned)(bbase + cc * 32 + q * 8);
  g[0] = *(const short8*)(base + si.x);
  g[1] = *(const short8*)(base + si.x + 256);
  g[2] = *(const short8*)(base + si.y);
  g[3] = *(const short8*)(base + si.y + 256);
}
__device__ inline void loadB(const unsigned short* __restrict__ wBt2, int wave,
                             int m16, int quad, int jt, short8* bf) {
  int cc = jt / 9, kt = jt - cc * 9;
  int ks = kt * 8 + cc;
  const unsigned short* bp =
      wBt2 + ((size_t)ks << 13) + (wave << 11) + m16 * 32 + quad * 8;
#pragma unroll
  for (int j = 0; j < 4; ++j)
    bf[j] = *(const short8*)(bp + j * 512);
}

// ------- Kernel 2: fused sample + MFMA GEMM, M-SPLIT across blocks -------
// grid 1024 = mh(1b) x b(3b) x h(6b). Each block owns a 32-px half-row:
// full K (72 iters), N=256 split across 4 waves (o = wave*64+j*16+m16),
// M-tile = 32 (acc[2][4] = 32 AGPRs/thread, HALF of round 0). Waves 0-1
// stage the 32-px A-tile (gather+bilinear, per-thread work unchanged);
// waves 2-3 are pure MFMA consumers. Zero inter-block dependencies —
// no flags, no spin, deadlock-impossible (rounds 2-4 post-mortem).
// Total gather/bilinear/MFMA work across the grid identical to round 0;
// only the tiny L2-resident B-panel is re-read per mh half.
// launch_bounds(256,4): unified cap 128; need ~(76 arch + 32 acc) = ~110,
// real headroom (round 1's failure was need ~150 > cap 128). Guarantees
// 16 waves/CU = 4 waves/SIMD — 2x round 0's latency hiding.
__global__ __launch_bounds__(256, 4) void deform_main(
    const unsigned short* __restrict__ xT, const float* __restrict__ offb,
    const unsigned short* __restrict__ wBt2, float* out) {
  __shared__ float4 smem4[752];                // 12032 B
  char* smem = (char*)smem4;
  float4* cwf4 = (float4*)smem;                          // 4608 B (288)
  int2*   cif2 = (int2*)(smem + 4608);                   // 2304 B (288)
  unsigned short* At = (unsigned short*)(smem + 6912);   // 2 x [32][40] bf16

  int tid = threadIdx.x, lane = tid & 63, wave = tid >> 6;
  int bid = blockIdx.x;
  int mh = bid & 1, b = (bid >> 1) & 7, h = bid >> 4;

  // --- coord precompute for OUR 32 px; offsets = 8 K-split partials + bias ---
  size_t bb = ((size_t)(b << 8)) << 12;
  for (int it = tid; it < 288; it += 256) {
    int k = it >> 5, lpx = it & 31;
    int px = mh * 32 + lpx;
    int ky = k / 3, kx = k - ky * 3;
    int idx = (h << 6) + px;
    float dy = offb[2 * k], dx = offb[2 * k + 1];
#pragma unroll
    for (int qq = 0; qq < 8; ++qq) {
      dy += out[bb + (((size_t)(100 + qq * 18 + 2 * k)) << 12) + idx];
      dx += out[bb + (((size_t)(101 + qq * 18 + 2 * k)) << 12) + idx];
    }
    float py = (float)(h - 1 + ky) + dy;
    float pxx = (float)(px - 1 + kx) + dx;
    float y0f = floorf(py), x0f = floorf(pxx);
    int y0 = (int)y0f, x0 = (int)x0f;
    float wy1 = py - y0f, wx1 = pxx - x0f;
    int xb; float wxl, wxr;
    if (x0 >= 0 && x0 <= 62)      { xb = x0; wxl = 1.f - wx1; wxr = wx1; }
    else if (x0 == -1)            { xb = 0;  wxl = wx1;       wxr = 0.f; }
    else if (x0 == 63)            { xb = 62; wxl = 0.f;       wxr = 1.f - wx1; }
    else                          { xb = 0;  wxl = 0.f;       wxr = 0.f; }
    float wy0v = ((unsigned)y0 < 64u) ? (1.f - wy1) : 0.f;
    float wy1v = ((unsigned)(y0 + 1) < 64u) ? wy1 : 0.f;
    int yc0 = min(max(y0, 0), 63), yc1 = min(max(y0 + 1, 0), 63);
    cwf4[it] = make_float4(wy0v * wxl, wy0v * wxr, wy1v * wxl, wy1v * wxr);
    cif2[it] = make_int2(((yc0 << 6) + xb) << 8, ((yc1 << 6) + xb) << 8);
  }
  __syncthreads();

  int m16 = lane & 15, quad = lane >> 4;
  int lpx = (wave & 1) * 16 + (lane >> 2);   // staging px for waves 0-1
  int q   = lane & 3;
  bool stager = (wave < 2);
  int bbase = b << 20;
  f32x4 acc[2][4];
#pragma unroll
  for (int i = 0; i < 2; ++i)
#pragma unroll
    for (int j = 0; j < 4; ++j) acc[i][j] = (f32x4){0.f, 0.f, 0.f, 0.f};

  short8 g[4]; float4 wq;
  if (stager) gather4(xT, bbase, q, 0, cif2, cwf4, lpx, g, wq);

  for (int it = 0; it < 72; ++it) {
    int buf = it & 1;
    short8 gn[4]; float4 wqn;
    if (stager) {
      short8 av;
#pragma unroll
      for (int i = 0; i < 8; ++i) {
        float v = wq.x * bf2f(g[0][i]) + wq.y * bf2f(g[1][i]) +
                  wq.z * bf2f(g[2][i]) + wq.w * bf2f(g[3][i]);
        av[i] = (short)f2bf(v);
      }
      *(short8*)(At + buf * 1280 + lpx * 40 + q * 8) = av;
      int jn = (it < 71) ? it + 1 : 71;
      gather4(xT, bbase, q, jn, cif2, cwf4, lpx, gn, wqn);
    }
    short8 bcur[4];
    loadB(wBt2, wave, m16, quad, it, bcur);   // L2-resident, no prefetch needed
    barrier_lgkm();
    short8 af[2];
#pragma unroll
    for (int mt = 0; mt < 2; ++mt)
      af[mt] = *(const short8*)(At + buf * 1280 + (mt * 16 + m16) * 40 + quad * 8);
#pragma unroll
    for (int mt = 0; mt < 2; ++mt)
#pragma unroll
      for (int j = 0; j < 4; ++j)
        acc[mt][j] = __builtin_amdgcn_mfma_f32_16x16x32_bf16(af[mt], bcur[j],
                                                             acc[mt][j], 0, 0, 0);
    if (stager) {
#pragma unroll
      for (int i = 0; i < 4; ++i) g[i] = gn[i];
      wq = wqn;
    }
  }

  // ---- epilogue: direct float4 stores from D-fragments ----
  // o = wave*64 + j*16 + m16 ; local px = mt*16 + quad*4 + r (r contiguous)
#pragma unroll
  for (int j = 0; j < 4; ++j) {
    int o = wave * 64 + j * 16 + m16;
    float* po = out + (((size_t)((b << 8) + o)) << 12) + (h << 6) + mh * 32 + quad * 4;
#pragma unroll
    for (int mt = 0; mt < 2; ++mt) {
      float4 v = make_float4(acc[mt][j][0], acc[mt][j][1], acc[mt][j][2],
                             acc[mt][j][3]);
      *(float4*)(po + mt * 16) = v;
    }
  }
}

extern "C" void kernel_launch(void* const* d_in, const int* in_sizes, int n_in,
                              void* d_out, int out_size, void* d_ws, size_t ws_size,
                              hipStream_t stream) {
  const float* x     = (const float*)d_in[0];
  const float* offw  = (const float*)d_in[1];
  const float* offb  = (const float*)d_in[2];
  const float* convw = (const float*)d_in[3];
  float* out = (float*)d_out;

  char* ws = (char*)d_ws;
  unsigned short* wOt   = (unsigned short*)ws;                // 147,456 B
  unsigned short* wOtLo = (unsigned short*)(ws + 147456);     // 147,456 B
  unsigned short* wBt2  = (unsigned short*)(ws + 294912);     // 1,179,648 B
  unsigned short* xT    = (unsigned short*)(ws + 1474560);    // 16,777,216 B
  unsigned short* xTlo  = (unsigned short*)(ws + 18251776);   // 16,777,216 B (end 35,028,992)
  const unsigned short* zp = wOt + 768;   // ks=0, o=24 row: guaranteed zeros

  prep_all<<<3616, 256, 0, stream>>>(x, convw, offw, xT, xTlo, wBt2, wOt, wOtLo);
  offset_conv3<<<4096, 64, 0, stream>>>(xT, xTlo, wOt, wOtLo, zp, out);
  deform_main<<<1024, 256, 0, stream>>>(xT, offb, wBt2, out);
}

// Round 6
// 196.966 us; speedup vs baseline: 1.3482x; 1.0768x over previous
//
#include <hip/hip_runtime.h>

using short8 = __attribute__((ext_vector_type(8))) short;
using f32x4  = __attribute__((ext_vector_type(4))) float;

__device__ inline unsigned short f2bf(float f) {
  unsigned u = __float_as_uint(f);
  u += 0x7fffu + ((u >> 16) & 1u);
  return (unsigned short)(u >> 16);
}
__device__ inline float bf2f(short s) {
  return __uint_as_float(((unsigned)(unsigned short)s) << 16);
}

// barrier that waits LDS only — global loads stay outstanding (pipeline!)
__device__ inline void barrier_lgkm() {
  asm volatile("s_waitcnt lgkmcnt(0)\n\ts_barrier" ::: "memory");
}

// ------- Kernel 0: ALL prep in one launch -------
// bid < 1024:             x NCHW fp32 -> xT (hi) + xTlo (residual) NHWC bf16
// 1024 <= bid < 3328:     conv weights -> wBt2[ks][o(256)][kc(32)]
// bid >= 3328:            offset weights -> wOt/wOtLo[ks][o(32, >=18 zero)][kc(32)]
__global__ __launch_bounds__(256) void prep_all(
    const float* __restrict__ x, const float* __restrict__ cw,
    const float* __restrict__ ow, unsigned short* __restrict__ xT,
    unsigned short* __restrict__ xTlo, unsigned short* __restrict__ wBt2,
    unsigned short* __restrict__ wOt, unsigned short* __restrict__ wOtLo) {
  __shared__ float tile[32 * 268];   // 34304 B (xT path only)
  int bid = blockIdx.x, tid = threadIdx.x;
  if (bid < 1024) {
    int xh = bid & 1, y = (bid >> 1) & 63, b = bid >> 7;
    int xc = tid & 31, cq = tid >> 5;
#pragma unroll 4
    for (int i = 0; i < 32; ++i) {
      int c = i * 8 + cq;
      tile[xc * 268 + c] =
          x[(((size_t)((b << 8) + c)) << 12) + (y << 6) + xh * 32 + xc];
    }
    __syncthreads();
#pragma unroll 2
    for (int i = 0; i < 8; ++i) {
      int u = i * 256 + tid;
      int site = u >> 6, c4 = u & 63;
      float4 v = *(const float4*)(tile + site * 268 + c4 * 4);
      ushort4 hi, lo;
      hi.x = f2bf(v.x); lo.x = f2bf(v.x - bf2f(hi.x));
      hi.y = f2bf(v.y); lo.y = f2bf(v.y - bf2f(hi.y));
      hi.z = f2bf(v.z); lo.z = f2bf(v.z - bf2f(hi.z));
      hi.w = f2bf(v.w); lo.w = f2bf(v.w - bf2f(hi.w));
      size_t addr = (((size_t)((b << 12) + (y << 6) + xh * 32 + site)) << 8) + c4 * 4;
      *(ushort4*)(xT + addr) = hi;
      *(ushort4*)(xTlo + addr) = lo;
    }
  } else if (bid < 3328) {
    int e = (bid - 1024) * 256 + tid;   // < 589824
    int kc = e & 31, o = (e >> 5) & 255, ks = e >> 13;
    int c = (ks & 7) * 32 + kc, kt = ks >> 3;
    wBt2[e] = f2bf(cw[(size_t)(o * 256 + c) * 9 + kt]);
  } else {
    int e = (bid - 3328) * 256 + tid;   // < 73728
    int kc = e & 31, o = (e >> 5) & 31, ks = e >> 10;
    int c = (ks & 7) * 32 + kc, kt = ks >> 3;
    float v = (o < 18) ? ow[(size_t)(o * 256 + c) * 9 + kt] : 0.f;
    unsigned short hi = f2bf(v);
    wOt[e] = hi;
    wOtLo[e] = f2bf(v - bf2f(hi));
  }
}

// ------- offset-conv helpers -------
__device__ inline void gatherOff2(const unsigned short* xT, const unsigned short* xTlo,
                                  const unsigned short* zp, int b, int h, int p16,
                                  int q, int ccg, int ky, int kx,
                                  short8* gh, short8* gl) {
  int y = h + ky - 1;
  bool yv = (unsigned)y < 64u;
  int yc = min(max(y, 0), 63);
#pragma unroll
  for (int i = 0; i < 4; ++i) {
    int px = i * 16 + p16;
    int xx = px + kx - 1;
    bool v = yv && ((unsigned)xx < 64u);
    int xc = min(max(xx, 0), 63);
    size_t base = (((size_t)((b << 12) + (yc << 6) + xc)) << 8) + ccg * 32 + q * 8;
    const unsigned short* ph = v ? (xT + base) : zp;
    const unsigned short* pl = v ? (xTlo + base) : zp;
    gh[i] = *(const short8*)ph;
    gl[i] = *(const short8*)pl;
  }
}
__device__ inline void loadBOff2(const unsigned short* wOt, const unsigned short* wOtLo,
                                 int ks, int m16, int quad, short8* bh, short8* bl) {
  const unsigned short* bp = wOt + (ks << 10) + m16 * 32 + quad * 8;
  const unsigned short* bq = wOtLo + (ks << 10) + m16 * 32 + quad * 8;
  bh[0] = *(const short8*)bp;  bh[1] = *(const short8*)(bp + 512);
  bl[0] = *(const short8*)bq;  bl[1] = *(const short8*)(bq + 512);
}

// ------- Kernel 1: offset conv via MFMA — barrier-free, 8-way K-split -------
// grid 4096 = ccq(8) x h(64) x b(8); 1 wave/block.
// SINGLE-buffered wave-local LDS (same-wave DS ops are in-order): 10.2 KB
// -> ~15 blocks/CU resident for latency hiding. (Passed rounds 2 & 5.)
__global__ __launch_bounds__(64) void offset_conv3(
    const unsigned short* __restrict__ xT, const unsigned short* __restrict__ xTlo,
    const unsigned short* __restrict__ wOt, const unsigned short* __restrict__ wOtLo,
    const unsigned short* __restrict__ zp, float* out) {
  __shared__ unsigned short Ah[2560], Al[2560];   // [64][40] each, single buf
  int lane = threadIdx.x;
  int bid = blockIdx.x;
  int b = bid & 7, h = (bid >> 3) & 63, ccq = bid >> 9;
  int m16 = lane & 15, quad = lane >> 4;
  int p16 = lane >> 2, q = lane & 3;
  f32x4 acc[4][2];
#pragma unroll
  for (int mt = 0; mt < 4; ++mt)
#pragma unroll
    for (int j = 0; j < 2; ++j) acc[mt][j] = (f32x4){0.f, 0.f, 0.f, 0.f};

  short8 gh[4], gl[4], bh[2], bl[2];
  gatherOff2(xT, xTlo, zp, b, h, p16, q, ccq, 0, 0, gh, gl);
  loadBOff2(wOt, wOtLo, ccq, m16, quad, bh, bl);

  for (int it = 0; it < 9; ++it) {
#pragma unroll
    for (int i = 0; i < 4; ++i) {
      int px = i * 16 + p16;
      *(short8*)(Ah + px * 40 + q * 8) = gh[i];
      *(short8*)(Al + px * 40 + q * 8) = gl[i];
    }
    int jn = (it < 8) ? it + 1 : 8;     // tap index (clamped; last discarded)
    int kyn = jn / 3, kxn = jn - kyn * 3;
    short8 ghn[4], gln[4], bhn[2], bln[2];
    loadBOff2(wOt, wOtLo, jn * 8 + ccq, m16, quad, bhn, bln);
    gatherOff2(xT, xTlo, zp, b, h, p16, q, ccq, kyn, kxn, ghn, gln);
    // wave-local LDS: same-wave DS ordering, no barrier needed
#pragma unroll
    for (int mt = 0; mt < 4; ++mt) {
      short8 ah = *(const short8*)(Ah + (mt * 16 + m16) * 40 + quad * 8);
      short8 al = *(const short8*)(Al + (mt * 16 + m16) * 40 + quad * 8);
#pragma unroll
      for (int j = 0; j < 2; ++j) {
        acc[mt][j] = __builtin_amdgcn_mfma_f32_16x16x32_bf16(ah, bh[j], acc[mt][j], 0, 0, 0);
        acc[mt][j] = __builtin_amdgcn_mfma_f32_16x16x32_bf16(al, bh[j], acc[mt][j], 0, 0, 0);
        acc[mt][j] = __builtin_amdgcn_mfma_f32_16x16x32_bf16(ah, bl[j], acc[mt][j], 0, 0, 0);
      }
    }
#pragma unroll
    for (int i = 0; i < 4; ++i) { gh[i] = ghn[i]; gl[i] = gln[i]; }
    bh[0] = bhn[0]; bh[1] = bhn[1]; bl[0] = bln[0]; bl[1] = bln[1];
  }
  // epilogue: D row = px (mt*16+quad*4+r), col = o (j*16+m16)
#pragma unroll
  for (int j = 0; j < 2; ++j) {
    int o = j * 16 + m16;
    if (o < 18) {
      float* po = out + (((size_t)((b << 8) + 100 + ccq * 18 + o)) << 12) + (h << 6);
#pragma unroll
      for (int mt = 0; mt < 4; ++mt)
#pragma unroll
        for (int rr = 0; rr < 4; ++rr)
          po[mt * 16 + quad * 4 + rr] = acc[mt][j][rr];
    }
  }
}

// ------- deform_main helpers -------
__device__ inline void gather4(const unsigned short* __restrict__ xT,
                               int bbase, int q, int jt,
                               const int2* cif2, const float4* cwf4,
                               int lpx, short8* g, float4& wq) {
  int cc = jt / 9, kt = jt - cc * 9;
  int2 si = cif2[kt * 128 + lpx];
  wq = cwf4[kt * 128 + lpx];
  const unsigned short* base = xT + (size_t)(unsigned)(bbase + cc * 32 + q * 8);
  g[0] = *(const short8*)(base + si.x);
  g[1] = *(const short8*)(base + si.x + 256);
  g[2] = *(const short8*)(base + si.y);
  g[3] = *(const short8*)(base + si.y + 256);
}
__device__ inline void loadB(const unsigned short* __restrict__ wBt2, int wc,
                             int m16, int quad, int jt, short8* bf) {
  int cc = jt / 9, kt = jt - cc * 9;
  int ks = kt * 8 + cc;
  const unsigned short* bp =
      wBt2 + ((size_t)ks << 13) + (wc << 11) + m16 * 32 + quad * 8;
#pragma unroll
  for (int j = 0; j < 4; ++j)
    bf[j] = *(const short8*)(bp + j * 512);
}

// ------- Kernel 2: fused sample + MFMA GEMM — M=128, fat barrier intervals ----
// Round-5 post-mortem: per barrier-interval time has a FIXED latency floor
// (gather L2 latency + barrier drain, ~700cy) that doesn't shrink with more
// waves; round 0 paid it 144x per CU, round 5 paid it 288x. This version
// pays it 72x: grid 256 = b(8) x h2(32), each block = TWO h-rows (M=128),
// 8 waves (wr = px-half, wc = o-panel). Every wave stages 16 px (per-thread
// staging identical to round 0) and runs the identical acc[4][4] MFMA body
// on its 64-px half x 64-o panel. Same total gather/B/MFMA work as round 0;
// HALF the barrier intervals, 2x issue work per interval. 1 block/CU
// (256 blocks, 32/XCD — exactly even). No inter-block sync (rounds 2-4 lesson).
// launch_bounds(512,2): register cap 256 unified — the proven 72-VGPR body
// compiles unchanged (round-1 lesson: never cap below the body's need).
__global__ __launch_bounds__(512, 2) void deform_main(
    const unsigned short* __restrict__ xT, const float* __restrict__ offb,
    const unsigned short* __restrict__ wBt2, float* out) {
  __shared__ float4 smem4[3008];               // 48128 B
  char* smem = (char*)smem4;
  float4* cwf4 = (float4*)smem;                          // 18432 B (1152)
  int2*   cif2 = (int2*)(smem + 18432);                  // 9216 B  (1152)
  unsigned short* At = (unsigned short*)(smem + 27648);  // 2 x [128][40] bf16

  int tid = threadIdx.x, lane = tid & 63, wave = tid >> 6;
  int bid = blockIdx.x;
  int b = bid & 7, h2 = bid >> 3;
  int wr = wave >> 2, wc = wave & 3;

  // --- coord precompute for 2 h-rows; offsets = 8 K-split partials + bias ---
  // entry layout: [k(9)][px128(128)], px128 = hrow*64 + px, h = h2*2 + hrow
  size_t bb = ((size_t)(b << 8)) << 12;
  for (int it = tid; it < 1152; it += 512) {
    int k = it >> 7, px128 = it & 127;
    int hrow = px128 >> 6, px = px128 & 63;
    int h = h2 * 2 + hrow;
    int ky = k / 3, kx = k - ky * 3;
    int idx = (h << 6) + px;
    float dy = offb[2 * k], dx = offb[2 * k + 1];
#pragma unroll
    for (int qq = 0; qq < 8; ++qq) {
      dy += out[bb + (((size_t)(100 + qq * 18 + 2 * k)) << 12) + idx];
      dx += out[bb + (((size_t)(101 + qq * 18 + 2 * k)) << 12) + idx];
    }
    float py = (float)(h - 1 + ky) + dy;
    float pxx = (float)(px - 1 + kx) + dx;
    float y0f = floorf(py), x0f = floorf(pxx);
    int y0 = (int)y0f, x0 = (int)x0f;
    float wy1 = py - y0f, wx1 = pxx - x0f;
    int xb; float wxl, wxr;
    if (x0 >= 0 && x0 <= 62)      { xb = x0; wxl = 1.f - wx1; wxr = wx1; }
    else if (x0 == -1)            { xb = 0;  wxl = wx1;       wxr = 0.f; }
    else if (x0 == 63)            { xb = 62; wxl = 0.f;       wxr = 1.f - wx1; }
    else                          { xb = 0;  wxl = 0.f;       wxr = 0.f; }
    float wy0v = ((unsigned)y0 < 64u) ? (1.f - wy1) : 0.f;
    float wy1v = ((unsigned)(y0 + 1) < 64u) ? wy1 : 0.f;
    int yc0 = min(max(y0, 0), 63), yc1 = min(max(y0 + 1, 0), 63);
    cwf4[it] = make_float4(wy0v * wxl, wy0v * wxr, wy1v * wxl, wy1v * wxr);
    cif2[it] = make_int2(((yc0 << 6) + xb) << 8, ((yc1 << 6) + xb) << 8);
  }
  __syncthreads();

  int m16 = lane & 15, quad = lane >> 4;
  int lpx = wave * 16 + (lane >> 2);   // this thread's staging row in [0,128)
  int q   = lane & 3;
  int bbase = b << 20;
  f32x4 acc[4][4];
#pragma unroll
  for (int i = 0; i < 4; ++i)
#pragma unroll
    for (int j = 0; j < 4; ++j) acc[i][j] = (f32x4){0.f, 0.f, 0.f, 0.f};

  short8 g[4]; float4 wq; short8 bcur[4];
  gather4(xT, bbase, q, 0, cif2, cwf4, lpx, g, wq);
  loadB(wBt2, wc, m16, quad, 0, bcur);

  for (int it = 0; it < 72; ++it) {
    int buf = it & 1;
    short8 av;
#pragma unroll
    for (int i = 0; i < 8; ++i) {
      float v = wq.x * bf2f(g[0][i]) + wq.y * bf2f(g[1][i]) +
                wq.z * bf2f(g[2][i]) + wq.w * bf2f(g[3][i]);
      av[i] = (short)f2bf(v);
    }
    *(short8*)(At + buf * 5120 + lpx * 40 + q * 8) = av;
    int jn = (it < 71) ? it + 1 : 71;
    short8 bnext[4], gn[4]; float4 wqn;
    loadB(wBt2, wc, m16, quad, jn, bnext);
    gather4(xT, bbase, q, jn, cif2, cwf4, lpx, gn, wqn);
    barrier_lgkm();
    short8 af[4];
#pragma unroll
    for (int mt = 0; mt < 4; ++mt)
      af[mt] = *(const short8*)(At + buf * 5120 +
                                (wr * 64 + mt * 16 + m16) * 40 + quad * 8);
#pragma unroll
    for (int mt = 0; mt < 4; ++mt)
#pragma unroll
      for (int j = 0; j < 4; ++j)
        acc[mt][j] = __builtin_amdgcn_mfma_f32_16x16x32_bf16(af[mt], bcur[j],
                                                             acc[mt][j], 0, 0, 0);
#pragma unroll
    for (int i = 0; i < 4; ++i) g[i] = gn[i];
    wq = wqn;
#pragma unroll
    for (int j = 0; j < 4; ++j) bcur[j] = bnext[j];
  }

  // ---- epilogue: direct float4 stores from D-fragments ----
  // o = wc*64 + j*16 + m16 ; h = h2*2 + wr ; px = mt*16 + quad*4 + r
#pragma unroll
  for (int j = 0; j < 4; ++j) {
    int o = wc * 64 + j * 16 + m16;
    float* po = out + (((size_t)((b << 8) + o)) << 12) +
                ((h2 * 2 + wr) << 6) + quad * 4;
#pragma unroll
    for (int mt = 0; mt < 4; ++mt) {
      float4 v = make_float4(acc[mt][j][0], acc[mt][j][1], acc[mt][j][2],
                             acc[mt][j][3]);
      *(float4*)(po + mt * 16) = v;
    }
  }
}

extern "C" void kernel_launch(void* const* d_in, const int* in_sizes, int n_in,
                              void* d_out, int out_size, void* d_ws, size_t ws_size,
                              hipStream_t stream) {
  const float* x     = (const float*)d_in[0];
  const float* offw  = (const float*)d_in[1];
  const float* offb  = (const float*)d_in[2];
  const float* convw = (const float*)d_in[3];
  float* out = (float*)d_out;

  char* ws = (char*)d_ws;
  unsigned short* wOt   = (unsigned short*)ws;                // 147,456 B
  unsigned short* wOtLo = (unsigned short*)(ws + 147456);     // 147,456 B
  unsigned short* wBt2  = (unsigned short*)(ws + 294912);     // 1,179,648 B
  unsigned short* xT    = (unsigned short*)(ws + 1474560);    // 16,777,216 B
  unsigned short* xTlo  = (unsigned short*)(ws + 18251776);   // 16,777,216 B (end 35,028,992)
  const unsigned short* zp = wOt + 768;   // ks=0, o=24 row: guaranteed zeros

  prep_all<<<3616, 256, 0, stream>>>(x, convw, offw, xT, xTlo, wBt2, wOt, wOtLo);
  offset_conv3<<<4096, 64, 0, stream>>>(xT, xTlo, wOt, wOtLo, zp, out);
  deform_main<<<256, 512, 0, stream>>>(xT, offb, wBt2, out);
}

// Round 7
// 189.468 us; speedup vs baseline: 1.4015x; 1.0396x over previous
//
#include <hip/hip_runtime.h>

using short8 = __attribute__((ext_vector_type(8))) short;
using f32x4  = __attribute__((ext_vector_type(4))) float;

__device__ inline unsigned short f2bf(float f) {
  unsigned u = __float_as_uint(f);
  u += 0x7fffu + ((u >> 16) & 1u);
  return (unsigned short)(u >> 16);
}
__device__ inline float bf2f(short s) {
  return __uint_as_float(((unsigned)(unsigned short)s) << 16);
}

// barrier that waits LDS only — global loads stay outstanding (pipeline!)
__device__ inline void barrier_lgkm() {
  asm volatile("s_waitcnt lgkmcnt(0)\n\ts_barrier" ::: "memory");
}

// ------- Kernel 0: ALL prep in one launch -------
// bid < 1024:             x NCHW fp32 -> xT (hi) + xTlo (residual) NHWC bf16
// 1024 <= bid < 3328:     conv weights -> wBt2[ks][o(256)][kc(32)]
// bid >= 3328:            offset weights -> wOt/wOtLo[ks][o(32, >=18 zero)][kc(32)]
__global__ __launch_bounds__(256) void prep_all(
    const float* __restrict__ x, const float* __restrict__ cw,
    const float* __restrict__ ow, unsigned short* __restrict__ xT,
    unsigned short* __restrict__ xTlo, unsigned short* __restrict__ wBt2,
    unsigned short* __restrict__ wOt, unsigned short* __restrict__ wOtLo) {
  __shared__ float tile[32 * 268];   // 34304 B (xT path only)
  int bid = blockIdx.x, tid = threadIdx.x;
  if (bid < 1024) {
    int xh = bid & 1, y = (bid >> 1) & 63, b = bid >> 7;
    int xc = tid & 31, cq = tid >> 5;
#pragma unroll 4
    for (int i = 0; i < 32; ++i) {
      int c = i * 8 + cq;
      tile[xc * 268 + c] =
          x[(((size_t)((b << 8) + c)) << 12) + (y << 6) + xh * 32 + xc];
    }
    __syncthreads();
#pragma unroll 2
    for (int i = 0; i < 8; ++i) {
      int u = i * 256 + tid;
      int site = u >> 6, c4 = u & 63;
      float4 v = *(const float4*)(tile + site * 268 + c4 * 4);
      ushort4 hi, lo;
      hi.x = f2bf(v.x); lo.x = f2bf(v.x - bf2f(hi.x));
      hi.y = f2bf(v.y); lo.y = f2bf(v.y - bf2f(hi.y));
      hi.z = f2bf(v.z); lo.z = f2bf(v.z - bf2f(hi.z));
      hi.w = f2bf(v.w); lo.w = f2bf(v.w - bf2f(hi.w));
      size_t addr = (((size_t)((b << 12) + (y << 6) + xh * 32 + site)) << 8) + c4 * 4;
      *(ushort4*)(xT + addr) = hi;
      *(ushort4*)(xTlo + addr) = lo;
    }
  } else if (bid < 3328) {
    int e = (bid - 1024) * 256 + tid;   // < 589824
    int kc = e & 31, o = (e >> 5) & 255, ks = e >> 13;
    int c = (ks & 7) * 32 + kc, kt = ks >> 3;
    wBt2[e] = f2bf(cw[(size_t)(o * 256 + c) * 9 + kt]);
  } else {
    int e = (bid - 3328) * 256 + tid;   // < 73728
    int kc = e & 31, o = (e >> 5) & 31, ks = e >> 10;
    int c = (ks & 7) * 32 + kc, kt = ks >> 3;
    float v = (o < 18) ? ow[(size_t)(o * 256 + c) * 9 + kt] : 0.f;
    unsigned short hi = f2bf(v);
    wOt[e] = hi;
    wOtLo[e] = f2bf(v - bf2f(hi));
  }
}

// ------- offset-conv helper (B-panel frag load, proven) -------
__device__ inline void loadBOff2(const unsigned short* wOt, const unsigned short* wOtLo,
                                 int ks, int m16, int quad, short8* bh, short8* bl) {
  const unsigned short* bp = wOt + (ks << 10) + m16 * 32 + quad * 8;
  const unsigned short* bq = wOtLo + (ks << 10) + m16 * 32 + quad * 8;
  bh[0] = *(const short8*)bp;  bh[1] = *(const short8*)(bp + 512);
  bl[0] = *(const short8*)bq;  bl[1] = *(const short8*)(bq + 512);
}

// ------- Kernel 1: offset conv — STAGED-ROW version (replaces 9-tap gather) ----
// grid 512 = b(3b) | h(6b); 256 threads = 4 waves.
// Old offset_conv3 gathered 9 taps as scattered 64B segments (50% line eff,
// ~576 KB per (b,h)) and wrote 8 partials that deform re-read with 16
// scattered loads per coord entry. New: each wave owns cc chunks {w, w+4};
// per chunk it stages the 3 NHWC rows (h-1,h,h+1) x 64px x 32ch, hi+lo, into
// wave-local LDS with COALESCED 64B/lane row copies (~196 KB per (b,h) total,
// streaming), zero-padded [3][66][40]-stride tile; the 9 taps become LDS
// reads at kx shifts. Cross-wave f32 reduce -> SINGLE partial written to
// overlay channels 100..117. No flags, no atomics, no inter-block deps.
__global__ __launch_bounds__(256) void offset_conv4(
    const unsigned short* __restrict__ xT, const unsigned short* __restrict__ xTlo,
    const unsigned short* __restrict__ wOt, const unsigned short* __restrict__ wOtLo,
    float* out) {
  // per wave: [buf(hi,lo)][ky(3)][pxp(66)][40 shorts (32 used; 40-stride = proven
  // bank-conflict-light layout from At tiles)] = 2*7920 shorts = 31,680 B
  __shared__ unsigned short S[4 * 2 * 7920];   // 126,720 B -> 1 block/CU, 512 blocks = 2 batches
  int tid = threadIdx.x, lane = tid & 63, wave = tid >> 6;
  int bid = blockIdx.x;
  int b = bid & 7, h = bid >> 3;
  int m16 = lane & 15, quad = lane >> 4;
  unsigned short* Sw = S + wave * 15840;       // hi at +0, lo at +7920

  // zero the pxp-pad rows (pxp = 0 and 65), all ky, both bufs: 12 rows x 32 sh
  {
    short8 z = (short8){0, 0, 0, 0, 0, 0, 0, 0};
    if (lane < 48) {
      int j = lane & 3, r = lane >> 2;          // r in 0..11
      int buf = r >= 6; int rr = r - buf * 6; int ky = rr >> 1, pad = rr & 1;
      int pxp = pad ? 65 : 0;
      *(short8*)(Sw + buf * 7920 + (ky * 66 + pxp) * 40 + j * 8) = z;
    }
  }

  f32x4 acc[4][2];
#pragma unroll
  for (int mt = 0; mt < 4; ++mt)
#pragma unroll
    for (int j = 0; j < 2; ++j) acc[mt][j] = (f32x4){0.f, 0.f, 0.f, 0.f};

  for (int ci = 0; ci < 2; ++ci) {
    int cc = wave + ci * 4;
    // ---- stage 3 rows (hi+lo) for chunk cc: lane = px, 64 B per row ----
#pragma unroll
    for (int ky = 0; ky < 3; ++ky) {
      int y = h + ky - 1;
      unsigned short* dh = Sw + (ky * 66 + lane + 1) * 40;
      unsigned short* dl = dh + 7920;
      if ((unsigned)y < 64u) {
        size_t base = (((size_t)((b << 12) + (y << 6) + lane)) << 8) + cc * 32;
        const unsigned short* sh_ = xT + base;
        const unsigned short* sl_ = xTlo + base;
#pragma unroll
        for (int j = 0; j < 4; ++j) {
          *(short8*)(dh + j * 8) = *(const short8*)(sh_ + j * 8);
          *(short8*)(dl + j * 8) = *(const short8*)(sl_ + j * 8);
        }
      } else {
        short8 z = (short8){0, 0, 0, 0, 0, 0, 0, 0};
#pragma unroll
        for (int j = 0; j < 4; ++j) {
          *(short8*)(dh + j * 8) = z;
          *(short8*)(dl + j * 8) = z;
        }
      }
    }
    // wave-local LDS: same-wave DS ordering, no barrier needed (offset_conv3-proven)
    // ---- 9 taps from LDS at kx shifts ----
    for (int kt = 0; kt < 9; ++kt) {
      int ky = kt / 3, kx = kt - ky * 3;
      short8 bh[2], bl[2];
      loadBOff2(wOt, wOtLo, kt * 8 + cc, m16, quad, bh, bl);
#pragma unroll
      for (int mt = 0; mt < 4; ++mt) {
        const unsigned short* ap = Sw + (ky * 66 + mt * 16 + m16 + kx) * 40 + quad * 8;
        short8 ah = *(const short8*)ap;
        short8 al = *(const short8*)(ap + 7920);
#pragma unroll
        for (int j = 0; j < 2; ++j) {
          acc[mt][j] = __builtin_amdgcn_mfma_f32_16x16x32_bf16(ah, bh[j], acc[mt][j], 0, 0, 0);
          acc[mt][j] = __builtin_amdgcn_mfma_f32_16x16x32_bf16(al, bh[j], acc[mt][j], 0, 0, 0);
          acc[mt][j] = __builtin_amdgcn_mfma_f32_16x16x32_bf16(ah, bl[j], acc[mt][j], 0, 0, 0);
        }
      }
    }
  }

  // ---- cross-wave f32 reduction (reuse S), single partial to overlay ----
  __syncthreads();
  float* red = (float*)S;   // [wv(4)][mt(4)][j(2)][lane(64)][4] = 32 KB
#pragma unroll
  for (int mt = 0; mt < 4; ++mt)
#pragma unroll
    for (int j = 0; j < 2; ++j)
      *(f32x4*)(red + ((((wave * 4 + mt) * 2) + j) * 64 + lane) * 4) = acc[mt][j];
  __syncthreads();
  // wave w sums mt = w over the 4 wave-partials; D: px = w*16+quad*4+r, o = j*16+m16
#pragma unroll
  for (int j = 0; j < 2; ++j) {
    int o = j * 16 + m16;
    f32x4 s = (f32x4){0.f, 0.f, 0.f, 0.f};
#pragma unroll
    for (int wv = 0; wv < 4; ++wv) {
      f32x4 v = *(const f32x4*)(red + ((((wv * 4 + wave) * 2) + j) * 64 + lane) * 4);
      s[0] += v[0]; s[1] += v[1]; s[2] += v[2]; s[3] += v[3];
    }
    if (o < 18) {
      float* po = out + (((size_t)((b << 8) + 100 + o)) << 12) + (h << 6) +
                  wave * 16 + quad * 4;
      *(float4*)po = make_float4(s[0], s[1], s[2], s[3]);
    }
  }
}

// ------- deform_main helpers (R0-proven, verbatim) -------
__device__ inline void gather4(const unsigned short* __restrict__ xT,
                               int bbase, int q, int jt,
                               const int2* cif2, const float4* cwf4,
                               int px, short8* g, float4& wq) {
  int cc = jt / 9, kt = jt - cc * 9;
  int2 si = cif2[kt * 64 + px];
  wq = cwf4[kt * 64 + px];
  const unsigned short* base = xT + (size_t)(unsigned)(bbase + cc * 32 + q * 8);
  g[0] = *(const short8*)(base + si.x);
  g[1] = *(const short8*)(base + si.x + 256);
  g[2] = *(const short8*)(base + si.y);
  g[3] = *(const short8*)(base + si.y + 256);
}
__device__ inline void loadB(const unsigned short* __restrict__ wBt2, int wave,
                             int m16, int quad, int jt, short8* bf) {
  int cc = jt / 9, kt = jt - cc * 9;
  int ks = kt * 8 + cc;
  const unsigned short* bp =
      wBt2 + ((size_t)ks << 13) + (wave << 11) + m16 * 32 + quad * 8;
#pragma unroll
  for (int j = 0; j < 4; ++j)
    bf[j] = *(const short8*)(bp + j * 512);
}

// ------- Kernel 2: fused sample + MFMA GEMM — EXACT round-0 structure -------
// (proven 80 µs / 72 VGPR). Only change: coord phase reads ONE offset partial
// (2 loads) instead of 8 partials (16 loads) per (k,px) entry.
__global__ __launch_bounds__(256, 2) void deform_main(
    const unsigned short* __restrict__ xT, const float* __restrict__ offb,
    const unsigned short* __restrict__ wBt2, float* out) {
  __shared__ float4 smem4[1504];               // 24064 B
  char* smem = (char*)smem4;
  float4* cwf4 = (float4*)smem;                          // 9216 B
  int2*   cif2 = (int2*)(smem + 9216);                   // 4608 B
  unsigned short* At = (unsigned short*)(smem + 13824);  // 2 x [64][40] bf16

  int tid = threadIdx.x, lane = tid & 63, wave = tid >> 6;
  int b = blockIdx.x & 7, h = blockIdx.x >> 3;

  // --- coord precompute; offsets = single staged partial + bias ---
  size_t bb = ((size_t)(b << 8)) << 12;
  for (int it = tid; it < 576; it += 256) {
    int k = it >> 6, px = it & 63;
    int ky = k / 3, kx = k - ky * 3;
    int idx = (h << 6) + px;
    float dy = offb[2 * k]     + out[bb + (((size_t)(100 + 2 * k)) << 12) + idx];
    float dx = offb[2 * k + 1] + out[bb + (((size_t)(101 + 2 * k)) << 12) + idx];
    float py = (float)(h - 1 + ky) + dy;
    float pxx = (float)(px - 1 + kx) + dx;
    float y0f = floorf(py), x0f = floorf(pxx);
    int y0 = (int)y0f, x0 = (int)x0f;
    float wy1 = py - y0f, wx1 = pxx - x0f;
    int xb; float wxl, wxr;
    if (x0 >= 0 && x0 <= 62)      { xb = x0; wxl = 1.f - wx1; wxr = wx1; }
    else if (x0 == -1)            { xb = 0;  wxl = wx1;       wxr = 0.f; }
    else if (x0 == 63)            { xb = 62; wxl = 0.f;       wxr = 1.f - wx1; }
    else                          { xb = 0;  wxl = 0.f;       wxr = 0.f; }
    float wy0v = ((unsigned)y0 < 64u) ? (1.f - wy1) : 0.f;
    float wy1v = ((unsigned)(y0 + 1) < 64u) ? wy1 : 0.f;
    int yc0 = min(max(y0, 0), 63), yc1 = min(max(y0 + 1, 0), 63);
    cwf4[it] = make_float4(wy0v * wxl, wy0v * wxr, wy1v * wxl, wy1v * wxr);
    cif2[it] = make_int2(((yc0 << 6) + xb) << 8, ((yc1 << 6) + xb) << 8);
  }
  __syncthreads();

  int m16 = lane & 15, quad = lane >> 4;
  int px = wave * 16 + (lane >> 2);
  int q  = lane & 3;
  int bbase = b << 20;
  f32x4 acc[4][4];
#pragma unroll
  for (int i = 0; i < 4; ++i)
#pragma unroll
    for (int j = 0; j < 4; ++j) acc[i][j] = (f32x4){0.f, 0.f, 0.f, 0.f};

  short8 g[4]; float4 wq; short8 bcur[4];
  gather4(xT, bbase, q, 0, cif2, cwf4, px, g, wq);
  loadB(wBt2, wave, m16, quad, 0, bcur);

  for (int it = 0; it < 72; ++it) {
    int buf = it & 1;
    short8 av;
#pragma unroll
    for (int i = 0; i < 8; ++i) {
      float v = wq.x * bf2f(g[0][i]) + wq.y * bf2f(g[1][i]) +
                wq.z * bf2f(g[2][i]) + wq.w * bf2f(g[3][i]);
      av[i] = (short)f2bf(v);
    }
    *(short8*)(At + buf * 2560 + px * 40 + q * 8) = av;
    int jn = (it < 71) ? it + 1 : 71;
    short8 bnext[4], gn[4]; float4 wqn;
    loadB(wBt2, wave, m16, quad, jn, bnext);
    gather4(xT, bbase, q, jn, cif2, cwf4, px, gn, wqn);
    barrier_lgkm();
    short8 af[4];
#pragma unroll
    for (int mt = 0; mt < 4; ++mt)
      af[mt] = *(const short8*)(At + buf * 2560 + (mt * 16 + m16) * 40 + quad * 8);
#pragma unroll
    for (int mt = 0; mt < 4; ++mt)
#pragma unroll
      for (int j = 0; j < 4; ++j)
        acc[mt][j] = __builtin_amdgcn_mfma_f32_16x16x32_bf16(af[mt], bcur[j],
                                                             acc[mt][j], 0, 0, 0);
#pragma unroll
    for (int i = 0; i < 4; ++i) g[i] = gn[i];
    wq = wqn;
#pragma unroll
    for (int j = 0; j < 4; ++j) bcur[j] = bnext[j];
  }

  // ---- epilogue: direct float4 stores from D-fragments ----
  // o = wave*64 + j*16 + m16 ; px = mt*16 + quad*4 + r (r contiguous)
#pragma unroll
  for (int j = 0; j < 4; ++j) {
    int o = wave * 64 + j * 16 + m16;
    float* po = out + (((size_t)((b << 8) + o)) << 12) + (h << 6) + quad * 4;
#pragma unroll
    for (int mt = 0; mt < 4; ++mt) {
      float4 v = make_float4(acc[mt][j][0], acc[mt][j][1], acc[mt][j][2],
                             acc[mt][j][3]);
      *(float4*)(po + mt * 16) = v;
    }
  }
}

extern "C" void kernel_launch(void* const* d_in, const int* in_sizes, int n_in,
                              void* d_out, int out_size, void* d_ws, size_t ws_size,
                              hipStream_t stream) {
  const float* x     = (const float*)d_in[0];
  const float* offw  = (const float*)d_in[1];
  const float* offb  = (const float*)d_in[2];
  const float* convw = (const float*)d_in[3];
  float* out = (float*)d_out;

  char* ws = (char*)d_ws;
  unsigned short* wOt   = (unsigned short*)ws;                // 147,456 B
  unsigned short* wOtLo = (unsigned short*)(ws + 147456);     // 147,456 B
  unsigned short* wBt2  = (unsigned short*)(ws + 294912);     // 1,179,648 B
  unsigned short* xT    = (unsigned short*)(ws + 1474560);    // 16,777,216 B
  unsigned short* xTlo  = (unsigned short*)(ws + 18251776);   // 16,777,216 B (end 35,028,992)

  prep_all<<<3616, 256, 0, stream>>>(x, convw, offw, xT, xTlo, wBt2, wOt, wOtLo);
  offset_conv4<<<512, 256, 0, stream>>>(xT, xTlo, wOt, wOtLo, out);
  deform_main<<<512, 256, 0, stream>>>(xT, offb, wBt2, out);
}